// Round 11
// baseline (126.284 us; speedup 1.0000x reference)
//
#include <hip/hip_runtime.h>
#include <hip/hip_bf16.h>
#include <cstdint>
#include <cstddef>

// Problem constants (fixed by the reference)
#define NCAT   8
#define DIN    64
#define HID    1024
#define NBATCH 256
#define HSEQ   64
#define NTOK   (NBATCH * HSEQ)   // 16384

typedef __bf16 bf16x8 __attribute__((ext_vector_type(8)));
typedef __bf16 bf16x4 __attribute__((ext_vector_type(4)));
typedef float  f32x4  __attribute__((ext_vector_type(4)));
typedef float  f32x16 __attribute__((ext_vector_type(16)));

__device__ __forceinline__ void async16(const void* g, void* l) {
    __builtin_amdgcn_global_load_lds(
        (const __attribute__((address_space(1))) unsigned int*)g,
        (__attribute__((address_space(3))) unsigned int*)l,
        16, 0, 0);
}

// ---------------- transpose helper (LDS buffer passed in) ----------------
// W [K][N] f32 tile -> Wt [N][K] bf16 (64x64)
__device__ __forceinline__ void transpose_tile_s(
        float (* __restrict__ tile)[65],
        const float* __restrict__ Wc, __bf16* __restrict__ Wtc,
        const int K, const int N, const int k0, const int n0) {
    const int t = threadIdx.x;
    const int cl = (t & 15) * 4, rw = t >> 4;
#pragma unroll
    for (int p = 0; p < 4; ++p) {
        const int r = rw + p * 16;
        const float4 v = *(const float4*)(Wc + (size_t)(k0 + r) * N + (n0 + cl));
        tile[r][cl]     = v.x;
        tile[r][cl + 1] = v.y;
        tile[r][cl + 2] = v.z;
        tile[r][cl + 3] = v.w;
    }
    __syncthreads();
    const int n = t >> 2, ks = (t & 3) * 16;
    bf16x8 o0, o1;
#pragma unroll
    for (int i = 0; i < 8; ++i) o0[i] = (__bf16)tile[ks + i][n];
#pragma unroll
    for (int i = 0; i < 8; ++i) o1[i] = (__bf16)tile[ks + 8 + i][n];
    __bf16* dst = Wtc + (size_t)(n0 + n) * K + (k0 + ks);
    *(bf16x8*)dst = o0;
    *(bf16x8*)(dst + 8) = o1;
}

// ---------------- merged prep ----------------
// bx==0: counting-sort batches by category -> order[256]
// bx 1..64: PE | bx 65..1088: x f32->bf16 | bx 1089..1216: W1 transpose
__global__ __launch_bounds__(256)
void prep_kernel(const int* __restrict__ cat, int* __restrict__ meta,
                 const float* __restrict__ x, __bf16* __restrict__ xb,
                 float* __restrict__ pe,
                 const float* __restrict__ W1, __bf16* __restrict__ W1t) {
    const int bx = blockIdx.x;
    const int tid = threadIdx.x;
    if (bx == 0) {
        __shared__ int scat[NBATCH];
        __shared__ int cnt[NCAT], pfx[NCAT + 1];
        const int c = cat[tid];
        scat[tid] = c;
        if (tid < NCAT) cnt[tid] = 0;
        __syncthreads();
        atomicAdd(&cnt[c], 1);
        __syncthreads();
        if (tid == 0) {
            pfx[0] = 0;
            for (int i = 0; i < NCAT; ++i) pfx[i + 1] = pfx[i] + cnt[i];
        }
        __syncthreads();
        int r = 0;
        for (int b = 0; b < tid; ++b) r += (scat[b] == c);
        meta[pfx[c] + r] = tid;                 // order[]: batches grouped by category
    } else if (bx <= 64) {
        const int t = bx - 1;                   // 0..63
#pragma unroll
        for (int s = 0; s < 2; ++s) {
            const int i = tid + s * 256;        // 0..511
            const float div = expf((float)(2 * i) * (-9.210340371976184f / 1024.f));
            const float a = (float)t * div;
            pe[t * HID + 2 * i]     = sinf(a);
            pe[t * HID + 2 * i + 1] = cosf(a);
        }
    } else if (bx <= 1088) {
        const size_t i = (size_t)(bx - 65) * 256 + tid;  // float4 index
        const float4 v = ((const float4*)x)[i];
        bf16x4 o = { (__bf16)v.x, (__bf16)v.y, (__bf16)v.z, (__bf16)v.w };
        *(bf16x4*)(xb + 4 * i) = o;
    } else {
        __shared__ float tile[64][65];
        const int i = bx - 1089;                // 0..127: 8 cat x 16 n-tiles
        const int c = i >> 4;
        const int n0 = (i & 15) * 64;
        transpose_tile_s(tile, W1 + (size_t)c * DIN * HID, W1t + (size_t)c * HID * DIN,
                         DIN, HID, 0, n0);
    }
}

// ---------------- GEMM core (R10 schedule, 32x32x16 MFMA) ----------------
// Block = one batch (64 rows, uniform category) x 256-col panel. 4 waves, each
// 64x64 as 2x2 of 32x32x16 MFMA (16 MFMA x 8.07cyc = 129 cyc/K-tile vs 32 x
// 4.85 = 155 for 16x16x32; same ds_read bytes). Stage-ahead double buffer
// (Ab 2x8K, Bb 2x32K = 80 KB, 2 blocks/CU), 2-barrier __syncthreads loop,
// gload_lds 16B, T2 slot-XOR swizzle on global source + ds_read.
// 32x32x16 fragments: A/B row = lane&31, k = (lane>>5)*8 + j (16B/lane);
// C/D col = lane&31, row = (reg&3) + 8*(reg>>2) + 4*(lane>>5)  [m74/m101].
// EPI: 0 = +bias, relu, +pe -> bf16 ; 1 = +bias, relu -> bf16 ; 2 = +bias -> f32
template <int K, int EPI>
__device__ __forceinline__ void gemm_core(
        char* __restrict__ smem,
        const __bf16* __restrict__ A, const __bf16* __restrict__ Bt,
        const float* __restrict__ bias, const float* __restrict__ pe,
        const int* __restrict__ order, const int* __restrict__ cat,
        __bf16* __restrict__ hout, float* __restrict__ fout,
        const int batchPos, const int panel) {
    const int tid = threadIdx.x;
    const int lane = tid & 63;
    const int wv = tid >> 6;             // 0..3 = n-quadrant
    const int batch = order[batchPos];
    const int cid = cat[batch];
    const int n0 = panel * 256;

    const char* Agb = (const char*)(A + (size_t)batch * HSEQ * K);
    const char* Bgb = (const char*)(Bt + ((size_t)cid * HID + n0) * K);

    const int srow = tid >> 3;           // 0..31
    const int scol_sw = (((tid & 7) ^ (srow & 7)) * 16);   // T2 pre-swizzled source

    auto Abuf = [&](int buf) { return smem + buf * 8192; };
    auto Bbuf = [&](int buf) { return smem + 16384 + buf * 32768; };

    auto stage = [&](int buf, int k0) {
        const size_t kb = (size_t)k0 * 2;
#pragma unroll
        for (int j = 0; j < 2; ++j) {    // A: 64 rows -> 2 issues
            const int row = j * 32 + srow;
            async16(Agb + (size_t)row * (K * 2) + kb + scol_sw,
                    Abuf(buf) + j * 4096 + tid * 16);
        }
#pragma unroll
        for (int j = 0; j < 8; ++j) {    // B: 256 rows -> 8 issues
            const int row = j * 32 + srow;
            async16(Bgb + (size_t)row * (K * 2) + kb + scol_sw,
                    Bbuf(buf) + j * 4096 + tid * 16);
        }
    };

    f32x16 acc[2][2] = {};
    const int l31 = lane & 31, l5 = lane >> 5;
    const int rsw = lane & 7;            // row&7 for all fragment rows

    const int NT = K / 64;
    stage(0, 0);
    __syncthreads();                     // buf0 staged (drains vmcnt)
    int cur = 0;
    for (int t = 0; t < NT; ++t) {
        if (t + 1 < NT) stage(cur ^ 1, (t + 1) * 64);  // issue-early
#pragma unroll
        for (int ks = 0; ks < 4; ++ks) { // 4 k-steps of 16
            const int soff = ((((ks << 1) | l5) ^ rsw) << 4);
            bf16x8 af[2], bfr[2];
#pragma unroll
            for (int mi = 0; mi < 2; ++mi)
                af[mi] = *(const bf16x8*)(Abuf(cur) + (mi * 32 + l31) * 128 + soff);
#pragma unroll
            for (int ni = 0; ni < 2; ++ni)
                bfr[ni] = *(const bf16x8*)(Bbuf(cur) + (wv * 64 + ni * 32 + l31) * 128 + soff);
#pragma unroll
            for (int mi = 0; mi < 2; ++mi)
#pragma unroll
                for (int ni = 0; ni < 2; ++ni)
                    acc[mi][ni] = __builtin_amdgcn_mfma_f32_32x32x16_bf16(
                        af[mi], bfr[ni], acc[mi][ni], 0, 0, 0);
        }
        __syncthreads();                 // next buf staged + reads of cur done
        cur ^= 1;
    }

    // epilogue: C/D col = lane&31, row = (reg&3) + 8*(reg>>2) + 4*(lane>>5)
    const int rbase = l5 * 4;
#pragma unroll
    for (int ni = 0; ni < 2; ++ni) {
        const int n = n0 + wv * 64 + ni * 32 + l31;
        const float bv = bias[cid * HID + n];
#pragma unroll
        for (int mi = 0; mi < 2; ++mi) {
#pragma unroll
            for (int reg = 0; reg < 16; ++reg) {
                const int tok = mi * 32 + (reg & 3) + 8 * (reg >> 2) + rbase;
                const size_t gi = ((size_t)batch * HSEQ + tok) * HID + n;
                float v = acc[mi][ni][reg] + bv;
                if constexpr (EPI == 0) {
                    v = fmaxf(v, 0.f) + pe[tok * HID + n];
                    hout[gi] = (__bf16)v;
                } else if constexpr (EPI == 1) {
                    v = fmaxf(v, 0.f);
                    hout[gi] = (__bf16)v;
                } else {
                    fout[gi] = v;
                }
            }
        }
    }
}

// XCD-chunked bijective mapping for a 1024-block GEMM grid:
// xcd = orig&7 owns sorted-batch positions [xcd*32, xcd*32+32) x all 4 panels.
__device__ __forceinline__ void xcd_map(int orig, int& batchPos, int& panel) {
    const int xcd = orig & 7;
    const int local = orig >> 3;         // 0..127
    batchPos = xcd * 32 + (local >> 2);  // 0..255, bijective
    panel = local & 3;
}

// ---------------- merged L1 GEMM (blocks 0..1023) + W2/W3 transpose (1024..5119) ----------------
__global__ __launch_bounds__(256, 2)
void gemm_l1_w23(const __bf16* __restrict__ A, const __bf16* __restrict__ Bt,
                 const float* __restrict__ bias, const float* __restrict__ pe,
                 const int* __restrict__ order, const int* __restrict__ cat,
                 __bf16* __restrict__ hout,
                 const float* __restrict__ W2, const float* __restrict__ W3,
                 __bf16* __restrict__ W2t, __bf16* __restrict__ W3t) {
    __shared__ __align__(16) char smem[81920];
    const int bx = blockIdx.x;
    if (bx < 1024) {
        int batchPos, panel;
        xcd_map(bx, batchPos, panel);
        gemm_core<DIN, 0>(smem, A, Bt, bias, pe, order, cat, hout, nullptr,
                          batchPos, panel);
    } else {
        const int i = bx - 1024;         // 0..4095
        const int z = i >> 8;            // 0..15: W2 cats 0-7, W3 cats 8-15
        const int c = z & 7;
        const int rem = i & 255;
        const int k0 = (rem >> 4) * 64, n0 = (rem & 15) * 64;
        const float* W = (z < 8) ? W2 : W3;
        __bf16* Wt = (z < 8) ? W2t : W3t;
        transpose_tile_s((float(*)[65])smem,
                         W + (size_t)c * HID * HID, Wt + (size_t)c * HID * HID,
                         HID, HID, k0, n0);
    }
}

__global__ __launch_bounds__(256, 2)
void gemm_l2(const __bf16* __restrict__ A, const __bf16* __restrict__ Bt,
             const float* __restrict__ bias,
             const int* __restrict__ order, const int* __restrict__ cat,
             __bf16* __restrict__ hout) {
    __shared__ __align__(16) char smem[81920];
    int batchPos, panel;
    xcd_map(blockIdx.x, batchPos, panel);
    gemm_core<HID, 1>(smem, A, Bt, bias, nullptr, order, cat, hout, nullptr,
                      batchPos, panel);
}
__global__ __launch_bounds__(256, 2)
void gemm_l3(const __bf16* __restrict__ A, const __bf16* __restrict__ Bt,
             const float* __restrict__ bias,
             const int* __restrict__ order, const int* __restrict__ cat,
             float* __restrict__ fout) {
    __shared__ __align__(16) char smem[81920];
    int batchPos, panel;
    xcd_map(blockIdx.x, batchPos, panel);
    gemm_core<HID, 2>(smem, A, Bt, bias, nullptr, order, cat, nullptr, fout,
                      batchPos, panel);
}

// ---------------- launcher (4 launches) ----------------

extern "C" void kernel_launch(void* const* d_in, const int* in_sizes, int n_in,
                              void* d_out, int out_size, void* d_ws, size_t ws_size,
                              hipStream_t stream) {
    (void)in_sizes; (void)n_in; (void)out_size; (void)ws_size;
    const float* x   = (const float*)d_in[0];
    const int*   cat = (const int*)d_in[1];
    const float* W1  = (const float*)d_in[2];
    const float* b1  = (const float*)d_in[3];
    const float* W2  = (const float*)d_in[4];
    const float* b2  = (const float*)d_in[5];
    const float* W3  = (const float*)d_in[6];
    const float* b3  = (const float*)d_in[7];
    float* out = (float*)d_out;

    // Workspace layout (67.1 MB; xb/W1t/pe are dead after L1 and time-alias h2):
    char* ws = (char*)d_ws;
    int*    meta = (int*)ws;                             // [0, 8192): order[256]
    __bf16* xb   = (__bf16*)(ws + 8192);                 // 2 MB   (L1 only)
    __bf16* W1t  = (__bf16*)(ws + 8192 + 2097152);       // 1 MB   (L1 only)
    float*  pe   = (float*) (ws + 8192 + 3145728);       // 256 KB (L1 only)
    __bf16* h2   = (__bf16*)(ws + 8192);                 // 32 MB  (aliases the above)
    __bf16* W2t  = (__bf16*)(ws + 33562624);             // 16 MB
    __bf16* W3t  = (__bf16*)(ws + 50339840);             // 16 MB
    // h1 (bf16, 32 MB) lives in the first half of d_out (f32 64 MB);
    // fully consumed by L2 before L3 overwrites d_out.
    __bf16* h1 = (__bf16*)d_out;

    prep_kernel<<<dim3(1217), dim3(256), 0, stream>>>(cat, meta, x, xb, pe, W1, W1t);
    gemm_l1_w23<<<dim3(5120), dim3(256), 0, stream>>>(xb, W1t, b1, pe, meta, cat, h1,
                                                      W2, W3, W2t, W3t);
    gemm_l2<<<dim3(1024), dim3(256), 0, stream>>>(h1, W2t, b2, meta, cat, h2);
    gemm_l3<<<dim3(1024), dim3(256), 0, stream>>>(h2, W3t, b3, meta, cat, out);
}

// Round 12
// 116.874 us; speedup vs baseline: 1.0805x; 1.0805x over previous
//
#include <hip/hip_runtime.h>
#include <hip/hip_bf16.h>
#include <cstdint>
#include <cstddef>

// Problem constants (fixed by the reference)
#define NCAT   8
#define DIN    64
#define HID    1024
#define NBATCH 256
#define HSEQ   64
#define NTOK   (NBATCH * HSEQ)   // 16384

typedef __bf16 bf16x8 __attribute__((ext_vector_type(8)));
typedef __bf16 bf16x4 __attribute__((ext_vector_type(4)));
typedef float  f32x4  __attribute__((ext_vector_type(4)));

__device__ __forceinline__ void async16(const void* g, void* l) {
    __builtin_amdgcn_global_load_lds(
        (const __attribute__((address_space(1))) unsigned int*)g,
        (__attribute__((address_space(3))) unsigned int*)l,
        16, 0, 0);
}

// ---------------- transpose helper (LDS buffer passed in) ----------------
// W [K][N] f32 tile -> Wt [N][K] bf16 (64x64)
__device__ __forceinline__ void transpose_tile_s(
        float (* __restrict__ tile)[65],
        const float* __restrict__ Wc, __bf16* __restrict__ Wtc,
        const int K, const int N, const int k0, const int n0) {
    const int t = threadIdx.x;
    const int cl = (t & 15) * 4, rw = t >> 4;
#pragma unroll
    for (int p = 0; p < 4; ++p) {
        const int r = rw + p * 16;
        const float4 v = *(const float4*)(Wc + (size_t)(k0 + r) * N + (n0 + cl));
        tile[r][cl]     = v.x;
        tile[r][cl + 1] = v.y;
        tile[r][cl + 2] = v.z;
        tile[r][cl + 3] = v.w;
    }
    __syncthreads();
    const int n = t >> 2, ks = (t & 3) * 16;
    bf16x8 o0, o1;
#pragma unroll
    for (int i = 0; i < 8; ++i) o0[i] = (__bf16)tile[ks + i][n];
#pragma unroll
    for (int i = 0; i < 8; ++i) o1[i] = (__bf16)tile[ks + 8 + i][n];
    __bf16* dst = Wtc + (size_t)(n0 + n) * K + (k0 + ks);
    *(bf16x8*)dst = o0;
    *(bf16x8*)(dst + 8) = o1;
}

// ---------------- merged prep ----------------
// bx==0: counting-sort batches by category -> order[256]
// bx 1..64: PE | bx 65..1088: x f32->bf16 | bx 1089..1216: W1 transpose
__global__ __launch_bounds__(256)
void prep_kernel(const int* __restrict__ cat, int* __restrict__ meta,
                 const float* __restrict__ x, __bf16* __restrict__ xb,
                 float* __restrict__ pe,
                 const float* __restrict__ W1, __bf16* __restrict__ W1t) {
    const int bx = blockIdx.x;
    const int tid = threadIdx.x;
    if (bx == 0) {
        __shared__ int scat[NBATCH];
        __shared__ int cnt[NCAT], pfx[NCAT + 1];
        const int c = cat[tid];
        scat[tid] = c;
        if (tid < NCAT) cnt[tid] = 0;
        __syncthreads();
        atomicAdd(&cnt[c], 1);
        __syncthreads();
        if (tid == 0) {
            pfx[0] = 0;
            for (int i = 0; i < NCAT; ++i) pfx[i + 1] = pfx[i] + cnt[i];
        }
        __syncthreads();
        int r = 0;
        for (int b = 0; b < tid; ++b) r += (scat[b] == c);
        meta[pfx[c] + r] = tid;                 // order[]: batches grouped by category
    } else if (bx <= 64) {
        const int t = bx - 1;                   // 0..63
#pragma unroll
        for (int s = 0; s < 2; ++s) {
            const int i = tid + s * 256;        // 0..511
            const float div = expf((float)(2 * i) * (-9.210340371976184f / 1024.f));
            const float a = (float)t * div;
            pe[t * HID + 2 * i]     = sinf(a);
            pe[t * HID + 2 * i + 1] = cosf(a);
        }
    } else if (bx <= 1088) {
        const size_t i = (size_t)(bx - 65) * 256 + tid;  // float4 index
        const float4 v = ((const float4*)x)[i];
        bf16x4 o = { (__bf16)v.x, (__bf16)v.y, (__bf16)v.z, (__bf16)v.w };
        *(bf16x4*)(xb + 4 * i) = o;
    } else {
        __shared__ float tile[64][65];
        const int i = bx - 1089;                // 0..127: 8 cat x 16 n-tiles
        const int c = i >> 4;
        const int n0 = (i & 15) * 64;
        transpose_tile_s(tile, W1 + (size_t)c * DIN * HID, W1t + (size_t)c * HID * DIN,
                         DIN, HID, 0, n0);
    }
}

// ---------------- GEMM core (R10 structure: best verified, 117 us wall) ----------------
// Block = one batch (64 rows, uniform category) x 256-col panel. 4 waves, each
// 64x64 (4x4 of 16x16x32 MFMA). Stage-ahead double buffer (Ab 2x8K, Bb 2x32K),
// 2-barrier __syncthreads loop, gload_lds 16B, T2 slot-XOR swizzle (2-way reads
// = free; 32x32 variant measured 4-way conflicted, reverted). XCD-chunked
// mapping by caller. EPI: 0 = +bias,relu,+pe -> bf16 ; 1 = +bias,relu -> bf16 ;
// 2 = +bias -> f32
template <int K, int EPI>
__device__ __forceinline__ void gemm_core(
        char* __restrict__ smem,
        const __bf16* __restrict__ A, const __bf16* __restrict__ Bt,
        const float* __restrict__ bias, const float* __restrict__ pe,
        const int* __restrict__ order, const int* __restrict__ cat,
        __bf16* __restrict__ hout, float* __restrict__ fout,
        const int batchPos, const int panel) {
    const int tid = threadIdx.x;
    const int lane = tid & 63;
    const int wv = tid >> 6;             // 0..3 = n-quadrant
    const int batch = order[batchPos];
    const int cid = cat[batch];
    const int n0 = panel * 256;

    const char* Agb = (const char*)(A + (size_t)batch * HSEQ * K);
    const char* Bgb = (const char*)(Bt + ((size_t)cid * HID + n0) * K);

    const int srow = tid >> 3;           // 0..31
    const int scol_sw = (((tid & 7) ^ (srow & 7)) * 16);   // T2 pre-swizzled source

    auto Abuf = [&](int buf) { return smem + buf * 8192; };
    auto Bbuf = [&](int buf) { return smem + 16384 + buf * 32768; };

    auto stage = [&](int buf, int k0) {
        const size_t kb = (size_t)k0 * 2;
#pragma unroll
        for (int j = 0; j < 2; ++j) {    // A: 64 rows -> 2 issues
            const int row = j * 32 + srow;
            async16(Agb + (size_t)row * (K * 2) + kb + scol_sw,
                    Abuf(buf) + j * 4096 + tid * 16);
        }
#pragma unroll
        for (int j = 0; j < 8; ++j) {    // B: 256 rows -> 8 issues
            const int row = j * 32 + srow;
            async16(Bgb + (size_t)row * (K * 2) + kb + scol_sw,
                    Bbuf(buf) + j * 4096 + tid * 16);
        }
    };

    f32x4 acc[4][4] = {};
    const int lr = lane & 15, lh = lane >> 4;
    const int rsw = lr & 7;

    const int NT = K / 64;
    stage(0, 0);
    __syncthreads();                     // buf0 staged (drains vmcnt)
    int cur = 0;
    for (int t = 0; t < NT; ++t) {
        if (t + 1 < NT) stage(cur ^ 1, (t + 1) * 64);  // issue-early
#pragma unroll
        for (int kk = 0; kk < 2; ++kk) {
            bf16x8 af[4], bfr[4];
            const int soff = ((((kk << 2) | lh) ^ rsw) << 4);
#pragma unroll
            for (int mi = 0; mi < 4; ++mi)
                af[mi] = *(const bf16x8*)(Abuf(cur) + (mi * 16 + lr) * 128 + soff);
#pragma unroll
            for (int ni = 0; ni < 4; ++ni)
                bfr[ni] = *(const bf16x8*)(Bbuf(cur) + (wv * 64 + ni * 16 + lr) * 128 + soff);
#pragma unroll
            for (int mi = 0; mi < 4; ++mi)
#pragma unroll
                for (int ni = 0; ni < 4; ++ni)
                    acc[mi][ni] = __builtin_amdgcn_mfma_f32_16x16x32_bf16(
                        af[mi], bfr[ni], acc[mi][ni], 0, 0, 0);
        }
        __syncthreads();                 // next buf staged + reads of cur done
        cur ^= 1;
    }

    // epilogue: C/D layout col = lane&15, row = (lane>>4)*4 + r
#pragma unroll
    for (int ni = 0; ni < 4; ++ni) {
        const int n = n0 + wv * 64 + ni * 16 + lr;
        const float bv = bias[cid * HID + n];
#pragma unroll
        for (int mi = 0; mi < 4; ++mi) {
#pragma unroll
            for (int r = 0; r < 4; ++r) {
                const int tok = mi * 16 + lh * 4 + r;   // token index = PE index
                const size_t gi = ((size_t)batch * HSEQ + tok) * HID + n;
                float v = acc[mi][ni][r] + bv;
                if constexpr (EPI == 0) {
                    v = fmaxf(v, 0.f) + pe[tok * HID + n];
                    hout[gi] = (__bf16)v;
                } else if constexpr (EPI == 1) {
                    v = fmaxf(v, 0.f);
                    hout[gi] = (__bf16)v;
                } else {
                    fout[gi] = v;
                }
            }
        }
    }
}

// XCD-chunked bijective mapping for a 1024-block GEMM grid:
// xcd = orig&7 owns sorted-batch positions [xcd*32, xcd*32+32) x all 4 panels.
__device__ __forceinline__ void xcd_map(int orig, int& batchPos, int& panel) {
    const int xcd = orig & 7;
    const int local = orig >> 3;         // 0..127
    batchPos = xcd * 32 + (local >> 2);  // 0..255, bijective
    panel = local & 3;
}

// ---------------- merged L1 GEMM (blocks 0..1023) + W2/W3 transpose (1024..5119) ----------------
__global__ __launch_bounds__(256, 2)
void gemm_l1_w23(const __bf16* __restrict__ A, const __bf16* __restrict__ Bt,
                 const float* __restrict__ bias, const float* __restrict__ pe,
                 const int* __restrict__ order, const int* __restrict__ cat,
                 __bf16* __restrict__ hout,
                 const float* __restrict__ W2, const float* __restrict__ W3,
                 __bf16* __restrict__ W2t, __bf16* __restrict__ W3t) {
    __shared__ __align__(16) char smem[81920];
    const int bx = blockIdx.x;
    if (bx < 1024) {
        int batchPos, panel;
        xcd_map(bx, batchPos, panel);
        gemm_core<DIN, 0>(smem, A, Bt, bias, pe, order, cat, hout, nullptr,
                          batchPos, panel);
    } else {
        const int i = bx - 1024;         // 0..4095
        const int z = i >> 8;            // 0..15: W2 cats 0-7, W3 cats 8-15
        const int c = z & 7;
        const int rem = i & 255;
        const int k0 = (rem >> 4) * 64, n0 = (rem & 15) * 64;
        const float* W = (z < 8) ? W2 : W3;
        __bf16* Wt = (z < 8) ? W2t : W3t;
        transpose_tile_s((float(*)[65])smem,
                         W + (size_t)c * HID * HID, Wt + (size_t)c * HID * HID,
                         HID, HID, k0, n0);
    }
}

__global__ __launch_bounds__(256, 2)
void gemm_l2(const __bf16* __restrict__ A, const __bf16* __restrict__ Bt,
             const float* __restrict__ bias,
             const int* __restrict__ order, const int* __restrict__ cat,
             __bf16* __restrict__ hout) {
    __shared__ __align__(16) char smem[81920];
    int batchPos, panel;
    xcd_map(blockIdx.x, batchPos, panel);
    gemm_core<HID, 1>(smem, A, Bt, bias, nullptr, order, cat, hout, nullptr,
                      batchPos, panel);
}
__global__ __launch_bounds__(256, 2)
void gemm_l3(const __bf16* __restrict__ A, const __bf16* __restrict__ Bt,
             const float* __restrict__ bias,
             const int* __restrict__ order, const int* __restrict__ cat,
             float* __restrict__ fout) {
    __shared__ __align__(16) char smem[81920];
    int batchPos, panel;
    xcd_map(blockIdx.x, batchPos, panel);
    gemm_core<HID, 2>(smem, A, Bt, bias, nullptr, order, cat, nullptr, fout,
                      batchPos, panel);
}

// ---------------- launcher (4 launches) ----------------

extern "C" void kernel_launch(void* const* d_in, const int* in_sizes, int n_in,
                              void* d_out, int out_size, void* d_ws, size_t ws_size,
                              hipStream_t stream) {
    (void)in_sizes; (void)n_in; (void)out_size; (void)ws_size;
    const float* x   = (const float*)d_in[0];
    const int*   cat = (const int*)d_in[1];
    const float* W1  = (const float*)d_in[2];
    const float* b1  = (const float*)d_in[3];
    const float* W2  = (const float*)d_in[4];
    const float* b2  = (const float*)d_in[5];
    const float* W3  = (const float*)d_in[6];
    const float* b3  = (const float*)d_in[7];
    float* out = (float*)d_out;

    // Workspace layout (67.1 MB; xb/W1t/pe are dead after L1 and time-alias h2):
    char* ws = (char*)d_ws;
    int*    meta = (int*)ws;                             // [0, 8192): order[256]
    __bf16* xb   = (__bf16*)(ws + 8192);                 // 2 MB   (L1 only)
    __bf16* W1t  = (__bf16*)(ws + 8192 + 2097152);       // 1 MB   (L1 only)
    float*  pe   = (float*) (ws + 8192 + 3145728);       // 256 KB (L1 only)
    __bf16* h2   = (__bf16*)(ws + 8192);                 // 32 MB  (aliases the above)
    __bf16* W2t  = (__bf16*)(ws + 33562624);             // 16 MB
    __bf16* W3t  = (__bf16*)(ws + 50339840);             // 16 MB
    // h1 (bf16, 32 MB) lives in the first half of d_out (f32 64 MB);
    // fully consumed by L2 before L3 overwrites d_out.
    __bf16* h1 = (__bf16*)d_out;

    prep_kernel<<<dim3(1217), dim3(256), 0, stream>>>(cat, meta, x, xb, pe, W1, W1t);
    gemm_l1_w23<<<dim3(5120), dim3(256), 0, stream>>>(xb, W1t, b1, pe, meta, cat, h1,
                                                      W2, W3, W2t, W3t);
    gemm_l2<<<dim3(1024), dim3(256), 0, stream>>>(h1, W2t, b2, meta, cat, h2);
    gemm_l3<<<dim3(1024), dim3(256), 0, stream>>>(h2, W3t, b3, meta, cat, out);
}